// Round 1
// baseline (490.111 us; speedup 1.0000x reference)
//
#include <hip/hip_runtime.h>
#include <hip/hip_bf16.h>

// Problem constants: B=4, S=2048, HID=128, NH=8, D_MODEL=1024
#define SEQ 2048
#define NBATCH 4
#define NHEAD 8
#define HDIM 128

typedef __attribute__((ext_vector_type(8))) short bf16x8;
typedef __attribute__((ext_vector_type(4))) float f32x4;

static __device__ __forceinline__ short f2b(float f) {
  union { float f; unsigned u; } v; v.f = f;
  unsigned r = (v.u + 0x7FFFu + ((v.u >> 16) & 1u)) >> 16;
  return (short)(unsigned short)r;
}
static __device__ __forceinline__ float b2f(short b) {
  union { unsigned u; float f; } v; v.u = ((unsigned)(unsigned short)b) << 16;
  return v.f;
}

// ---------------- 1) x fp32 -> bf16 (vectorized) ----------------
__global__ __launch_bounds__(256) void k_cvt_x(const float* __restrict__ x,
                                               short* __restrict__ xb) {
  int i = blockIdx.x * blockDim.x + threadIdx.x; // 131072 threads, 8 elems each
  const float4* p = reinterpret_cast<const float4*>(x) + (size_t)i * 2;
  float4 a = p[0], c = p[1];
  bf16x8 o;
  o[0] = f2b(a.x); o[1] = f2b(a.y); o[2] = f2b(a.z); o[3] = f2b(a.w);
  o[4] = f2b(c.x); o[5] = f2b(c.y); o[6] = f2b(c.z); o[7] = f2b(c.w);
  reinterpret_cast<bf16x8*>(xb)[i] = o;
}

// ---------------- 2) W_qkv [128][3072] -> Wqt bf16 [3072][128] ----------------
__global__ __launch_bounds__(256) void k_wqkv(const float* __restrict__ w,
                                              short* __restrict__ wt) {
  int tid = blockIdx.x * blockDim.x + threadIdx.x; // 393216
  int k = tid & 127, j = tid >> 7;
  wt[tid] = f2b(w[(size_t)k * 3072 + j]); // coalesced write, L2-cached strided read
}

// ---------------- 3) W_o [1024][128] -> Wot bf16 [128][1024] ----------------
__global__ __launch_bounds__(256) void k_wo(const float* __restrict__ w,
                                            short* __restrict__ wt) {
  int tid = blockIdx.x * blockDim.x + threadIdx.x; // 131072
  int k = tid & 1023, c = tid >> 10;
  wt[tid] = f2b(w[(size_t)k * 128 + c]);
}

// ---------------- 4) QKV GEMM: xb[8192][128] @ Wqt^T -> Q,K,V ----------------
// block: 256 thr / 4 waves; tile M=64 (wave=16 rows), N=128; K=128 in 4 steps.
__global__ __launch_bounds__(256) void k_qkv(const short* __restrict__ xb,
                                             const short* __restrict__ wqt,
                                             const float* __restrict__ bias,
                                             short* __restrict__ Qb,
                                             short* __restrict__ Kb,
                                             short* __restrict__ Vr) {
  int wave = threadIdx.x >> 6, lane = threadIdx.x & 63;
  int lr = lane & 15, lg = lane >> 4;
  int m0 = blockIdx.y * 64 + wave * 16;
  int j0 = blockIdx.x * 128;

  bf16x8 a[4];
#pragma unroll
  for (int ks = 0; ks < 4; ++ks)
    a[ks] = *reinterpret_cast<const bf16x8*>(xb + (size_t)(m0 + lr) * 128 + ks * 32 + lg * 8);

  f32x4 acc[8];
#pragma unroll
  for (int nf = 0; nf < 8; ++nf) acc[nf] = (f32x4){0.f, 0.f, 0.f, 0.f};

#pragma unroll
  for (int ks = 0; ks < 4; ++ks) {
#pragma unroll
    for (int nf = 0; nf < 8; ++nf) {
      bf16x8 bfr = *reinterpret_cast<const bf16x8*>(
          wqt + (size_t)(j0 + nf * 16 + lr) * 128 + ks * 32 + lg * 8);
      acc[nf] = __builtin_amdgcn_mfma_f32_16x16x32_bf16(a[ks], bfr, acc[nf], 0, 0, 0);
    }
  }

#pragma unroll
  for (int nf = 0; nf < 8; ++nf) {
    int j = j0 + nf * 16 + lr;
    float bv = bias[j];
    int sel = j >> 10;  // 0=Q 1=K 2=V
    int jj = j & 1023;
    int h = jj >> 7, c = jj & 127;
#pragma unroll
    for (int r = 0; r < 4; ++r) {
      int sg = m0 + lg * 4 + r;           // global row in [0,8192)
      int bb = sg >> 11, s = sg & 2047;   // batch, seq
      short v = f2b(acc[nf][r] + bv);
      size_t bh = (size_t)(bb * NHEAD + h);
      if (sel == 0)      Qb[(bh * SEQ + s) * HDIM + c] = v;
      else if (sel == 1) Kb[(bh * SEQ + s) * HDIM + c] = v;
      else               Vr[(bh * SEQ + s) * HDIM + c] = v;
    }
  }
}

// ---------------- 5) V row-major -> Vt [bh][c][t] (LDS 64x64 tile transpose) ----
__global__ __launch_bounds__(256) void k_vt(const short* __restrict__ Vr,
                                            short* __restrict__ Vt) {
  __shared__ short tile[64][73];
  int bh = blockIdx.z;
  int t0 = blockIdx.y * 64, c0 = blockIdx.x * 64;
  const short* src = Vr + (size_t)bh * SEQ * HDIM;
  short* dst = Vt + (size_t)bh * HDIM * SEQ;
  int rr = threadIdx.x >> 3, cc = (threadIdx.x & 7) * 8;
#pragma unroll
  for (int p = 0; p < 2; ++p) {
    int r = rr + p * 32;
    bf16x8 v = *reinterpret_cast<const bf16x8*>(src + (size_t)(t0 + r) * HDIM + c0 + cc);
#pragma unroll
    for (int jx = 0; jx < 8; ++jx) tile[r][cc + jx] = v[jx];
  }
  __syncthreads();
#pragma unroll
  for (int p = 0; p < 2; ++p) {
    int r = rr + p * 32;  // row within c-dim
    bf16x8 v;
#pragma unroll
    for (int jx = 0; jx < 8; ++jx) v[jx] = tile[cc + jx][r];
    *reinterpret_cast<bf16x8*>(dst + (size_t)(c0 + r) * SEQ + t0 + cc) = v;
  }
}

// ---------------- 6) Tot[bh][c] = sum_t V[bh][t][c]  (reads Vt rows) -----------
__global__ __launch_bounds__(256) void k_tot(const short* __restrict__ Vt,
                                             float* __restrict__ Tot) {
  int wave = threadIdx.x >> 6, lane = threadIdx.x & 63;
  int row = blockIdx.x * 4 + wave;  // 4096 rows of length 2048
  const short* p = Vt + (size_t)row * SEQ;
  float s = 0.f;
#pragma unroll
  for (int k = 0; k < 4; ++k) {
    bf16x8 v = *reinterpret_cast<const bf16x8*>(p + k * 512 + lane * 8);
#pragma unroll
    for (int jx = 0; jx < 8; ++jx) s += b2f(v[jx]);
  }
#pragma unroll
  for (int off = 32; off > 0; off >>= 1) s += __shfl_down(s, off, 64);
  if (lane == 0) Tot[row] = s;
}

// ---------------- 7) Attention: out = (1/8)Tot + sum_{t>=s} (alpha_h - 1/8) V --
// grid (64,4): blockIdx.x = pair index i -> s-tiles {16*i, 16*(127-i)}, y = batch
// 512 threads = 8 waves, wave h owns head h. t-tiles of 32.
__global__ __launch_bounds__(512, 2) void k_attn(const short* __restrict__ Qb,
                                                 const short* __restrict__ Kb,
                                                 const short* __restrict__ Vt,
                                                 const float* __restrict__ Tot,
                                                 short* __restrict__ Ob) {
  __shared__ float Sm[8][16][33];  // scores exchange, fp32
  __shared__ short Pm[8][16][48];  // alpha-1/8 bf16, padded to 96B rows (16B aligned)
  int tid = threadIdx.x;
  int h = tid >> 6, lane = tid & 63, lr = lane & 15, lg = lane >> 4;
  int i = blockIdx.x, b = blockIdx.y;
  int bh = b * NHEAD + h;
  const short* Qh = Qb + (size_t)bh * SEQ * HDIM;
  const short* Kh = Kb + (size_t)bh * SEQ * HDIM;
  const short* Vh = Vt + (size_t)bh * HDIM * SEQ;
  int s0[2] = {i * 16, (127 - i) * 16};
  int ttmin[2] = {i >> 1, (127 - i) >> 1};

  bf16x8 qa[2][4];
#pragma unroll
  for (int w = 0; w < 2; ++w)
#pragma unroll
    for (int ks = 0; ks < 4; ++ks)
      qa[w][ks] = *reinterpret_cast<const bf16x8*>(
          Qh + (size_t)(s0[w] + lr) * HDIM + ks * 32 + lg * 8);

  f32x4 oa[2][8];
#pragma unroll
  for (int w = 0; w < 2; ++w)
#pragma unroll
    for (int cf = 0; cf < 8; ++cf) oa[w][cf] = (f32x4){0.f, 0.f, 0.f, 0.f};

  int ssx = tid >> 5, tlx = tid & 31;  // this thread's softmax element

  for (int tt = ttmin[0]; tt < 64; ++tt) {
    int t0 = tt * 32;
    bf16x8 kf[2][4], vf[8];
#pragma unroll
    for (int nf = 0; nf < 2; ++nf)
#pragma unroll
      for (int ks = 0; ks < 4; ++ks)
        kf[nf][ks] = *reinterpret_cast<const bf16x8*>(
            Kh + (size_t)(t0 + nf * 16 + lr) * HDIM + ks * 32 + lg * 8);
#pragma unroll
    for (int cf = 0; cf < 8; ++cf)
      vf[cf] = *reinterpret_cast<const bf16x8*>(
          Vh + (size_t)(cf * 16 + lr) * SEQ + t0 + lg * 8);

#pragma unroll
    for (int w = 0; w < 2; ++w) {
      if (tt < ttmin[w]) continue;  // uniform across block: no barrier divergence
      // QK^T -> S tile [16 s][32 t], head h
      f32x4 sf[2];
      sf[0] = (f32x4){0.f, 0.f, 0.f, 0.f};
      sf[1] = (f32x4){0.f, 0.f, 0.f, 0.f};
#pragma unroll
      for (int ks = 0; ks < 4; ++ks) {
        sf[0] = __builtin_amdgcn_mfma_f32_16x16x32_bf16(qa[w][ks], kf[0][ks], sf[0], 0, 0, 0);
        sf[1] = __builtin_amdgcn_mfma_f32_16x16x32_bf16(qa[w][ks], kf[1][ks], sf[1], 0, 0, 0);
      }
#pragma unroll
      for (int nf = 0; nf < 2; ++nf)
#pragma unroll
        for (int r = 0; r < 4; ++r) Sm[h][lg * 4 + r][nf * 16 + lr] = sf[nf][r];
      __syncthreads();

      // cross-head softmax: one (s,t) element per thread
      {
        int sg = s0[w] + ssx, tg = t0 + tlx;
        if (tg >= sg) {
          float e[8];
          float mx = -1e30f;
#pragma unroll
          for (int hh = 0; hh < 8; ++hh) {
            e[hh] = Sm[hh][ssx][tlx] * 0.03125f;  // /32 = /sqrt(1024)
            mx = fmaxf(mx, e[hh]);
          }
          float sum = 0.f;
#pragma unroll
          for (int hh = 0; hh < 8; ++hh) { e[hh] = __expf(e[hh] - mx); sum += e[hh]; }
          float inv = 1.f / sum;
#pragma unroll
          for (int hh = 0; hh < 8; ++hh) Pm[hh][ssx][tlx] = f2b(e[hh] * inv - 0.125f);
        } else {
#pragma unroll
          for (int hh = 0; hh < 8; ++hh) Pm[hh][ssx][tlx] = 0;
        }
      }
      __syncthreads();

      // PV: P[16s][32t] @ V[32t][128c]
      bf16x8 pa = *reinterpret_cast<const bf16x8*>(&Pm[h][lr][lg * 8]);
#pragma unroll
      for (int cf = 0; cf < 8; ++cf)
        oa[w][cf] = __builtin_amdgcn_mfma_f32_16x16x32_bf16(pa, vf[cf], oa[w][cf], 0, 0, 0);
    }
  }

  // epilogue: add (1/8)*Tot, write bf16 [b][s][h*128+c]
#pragma unroll
  for (int w = 0; w < 2; ++w) {
#pragma unroll
    for (int cf = 0; cf < 8; ++cf) {
      int c = cf * 16 + lr;
      float tot = Tot[bh * HDIM + c] * 0.125f;
#pragma unroll
      for (int r = 0; r < 4; ++r) {
        int sg = s0[w] + lg * 4 + r;
        Ob[((size_t)(b * SEQ + sg)) * 1024 + h * HDIM + c] = f2b(oa[w][cf][r] + tot);
      }
    }
  }
}

// ---------------- 8) Output GEMM: Ob[8192][1024] @ Wot^T + b_o -> fp32 ----------
__global__ __launch_bounds__(256) void k_out(const short* __restrict__ Ob,
                                             const short* __restrict__ wot,
                                             const float* __restrict__ bo,
                                             float* __restrict__ out) {
  int wave = threadIdx.x >> 6, lane = threadIdx.x & 63;
  int lr = lane & 15, lg = lane >> 4;
  int m0 = blockIdx.x * 64 + wave * 16;
  f32x4 acc[8];
#pragma unroll
  for (int nf = 0; nf < 8; ++nf) acc[nf] = (f32x4){0.f, 0.f, 0.f, 0.f};
  for (int ks = 0; ks < 32; ++ks) {
    bf16x8 a = *reinterpret_cast<const bf16x8*>(Ob + (size_t)(m0 + lr) * 1024 + ks * 32 + lg * 8);
#pragma unroll
    for (int nf = 0; nf < 8; ++nf) {
      bf16x8 bfr = *reinterpret_cast<const bf16x8*>(
          wot + (size_t)(nf * 16 + lr) * 1024 + ks * 32 + lg * 8);
      acc[nf] = __builtin_amdgcn_mfma_f32_16x16x32_bf16(a, bfr, acc[nf], 0, 0, 0);
    }
  }
#pragma unroll
  for (int nf = 0; nf < 8; ++nf) {
    int c = nf * 16 + lr;
    float bv = bo[c];
#pragma unroll
    for (int r = 0; r < 4; ++r)
      out[(size_t)(m0 + lg * 4 + r) * 128 + c] = acc[nf][r] + bv;
  }
}

extern "C" void kernel_launch(void* const* d_in, const int* in_sizes, int n_in,
                              void* d_out, int out_size, void* d_ws, size_t ws_size,
                              hipStream_t stream) {
  const float* x    = (const float*)d_in[0];
  const float* wqkv = (const float*)d_in[1];
  const float* bqkv = (const float*)d_in[2];
  const float* wo   = (const float*)d_in[3];
  const float* bo   = (const float*)d_in[4];
  // d_in[5] = num_heads (hardcoded 8)

  char* ws = (char*)d_ws;
  const size_t MB = (size_t)1 << 20;
  short* xb  = (short*)(ws + 0);        //  2 MB  : x bf16 [8192][128]
  short* wqt = (short*)(ws + 2 * MB);   //  .75MB : W_qkv^T bf16 [3072][128]
  short* wot = (short*)(ws + 3 * MB);   //  .25MB : W_o^T bf16 [128][1024]
  short* Qb  = (short*)(ws + 4 * MB);   // 16 MB  : [bh][s][c]
  short* Kb  = (short*)(ws + 20 * MB);  // 16 MB  : [bh][t][c]
  short* Vr  = (short*)(ws + 36 * MB);  // 16 MB  : [bh][t][c] (dead after k_vt)
  short* Vt  = (short*)(ws + 52 * MB);  // 16 MB  : [bh][c][t]
  float* Tot = (float*)(ws + 68 * MB);  // 16 KB  : [bh][c]
  short* Ob  = (short*)(ws + 36 * MB);  // 16 MB  : aliases Vr (safe: stream-ordered)

  hipLaunchKernelGGL(k_cvt_x, dim3(512), dim3(256), 0, stream, x, xb);
  hipLaunchKernelGGL(k_wqkv, dim3(1536), dim3(256), 0, stream, wqkv, wqt);
  hipLaunchKernelGGL(k_wo, dim3(512), dim3(256), 0, stream, wo, wot);
  hipLaunchKernelGGL(k_qkv, dim3(24, 128), dim3(256), 0, stream, xb, wqt, bqkv, Qb, Kb, Vr);
  hipLaunchKernelGGL(k_vt, dim3(2, 32, 32), dim3(256), 0, stream, Vr, Vt);
  hipLaunchKernelGGL(k_tot, dim3(1024), dim3(256), 0, stream, Vt, Tot);
  hipLaunchKernelGGL(k_attn, dim3(64, 4), dim3(512), 0, stream, Qb, Kb, Vt, Tot, Ob);
  hipLaunchKernelGGL(k_out, dim3(128), dim3(256), 0, stream, Ob, wot, bo, (float*)d_out);
}

// Round 2
// 374.394 us; speedup vs baseline: 1.3091x; 1.3091x over previous
//
#include <hip/hip_runtime.h>
#include <hip/hip_bf16.h>

// Problem constants: B=4, S=2048, HID=128, NH=8, D_MODEL=1024
#define SEQ 2048
#define NHEAD 8
#define HDIM 128

typedef __attribute__((ext_vector_type(8))) short bf16x8;
typedef __attribute__((ext_vector_type(4))) float f32x4;
typedef long i64;
typedef unsigned long long u64;

static __device__ __forceinline__ short f2b(float f) {
  union { float f; unsigned u; } v; v.f = f;
  unsigned r = (v.u + 0x7FFFu + ((v.u >> 16) & 1u)) >> 16;
  return (short)(unsigned short)r;
}
static __device__ __forceinline__ float b2f(short b) {
  union { unsigned u; float f; } v; v.u = ((unsigned)(unsigned short)b) << 16;
  return v.f;
}
// OCP e4m3fn encode, RTN-even for normals, denorms handled, saturate at 448.
static __device__ __forceinline__ unsigned f2e4m3(float x) {
  union { float f; unsigned u; } v; v.f = x;
  unsigned s = (v.u >> 24) & 0x80u;
  unsigned a = v.u & 0x7FFFFFFFu;
  if (a > 0x43E00000u) a = 0x43E00000u;      // clamp |x| to 448
  if (a < 0x3C800000u) {                     // |x| < 2^-6 : denormal domain
    union { unsigned u; float f; } w; w.u = a;
    return s | (unsigned)(int)(w.f * 512.0f + 0.5f);
  }
  a += 0x7FFFFu + ((a >> 20) & 1u);          // round to 3 mantissa bits
  return s | (((a >> 23) - 120u) << 3) | ((a >> 20) & 7u);
}

// ---------------- 1) x fp32 -> bf16 ----------------
__global__ __launch_bounds__(256) void k_cvt_x(const float* __restrict__ x,
                                               short* __restrict__ xb) {
  int i = blockIdx.x * blockDim.x + threadIdx.x;
  const float4* p = reinterpret_cast<const float4*>(x) + (size_t)i * 2;
  float4 a = p[0], c = p[1];
  bf16x8 o;
  o[0] = f2b(a.x); o[1] = f2b(a.y); o[2] = f2b(a.z); o[3] = f2b(a.w);
  o[4] = f2b(c.x); o[5] = f2b(c.y); o[6] = f2b(c.z); o[7] = f2b(c.w);
  reinterpret_cast<bf16x8*>(xb)[i] = o;
}

// ---------------- 2) W_qkv [128][3072] -> Wqt bf16 [3072][128] ----------------
__global__ __launch_bounds__(256) void k_wqkv(const float* __restrict__ w,
                                              short* __restrict__ wt) {
  int tid = blockIdx.x * blockDim.x + threadIdx.x;
  int k = tid & 127, j = tid >> 7;
  wt[tid] = f2b(w[(size_t)k * 3072 + j]);
}

// ---------------- 3) W_o [1024][128] -> Wot bf16 [128][1024] ----------------
__global__ __launch_bounds__(256) void k_wo(const float* __restrict__ w,
                                            short* __restrict__ wt) {
  int tid = blockIdx.x * blockDim.x + threadIdx.x;
  int k = tid & 1023, c = tid >> 10;
  wt[tid] = f2b(w[(size_t)k * 128 + c]);
}

// ---------------- 4) QKV GEMM -> Qf,Kf fp8 [bh][s][c]; Vt fp8 [bh][c][t] -------
// Scales: Q*4, K*4, V*16 (decoded later). V written pre-transposed (kills k_vt).
__global__ __launch_bounds__(256) void k_qkv(const short* __restrict__ xb,
                                             const short* __restrict__ wqt,
                                             const float* __restrict__ bias,
                                             unsigned char* __restrict__ Qf,
                                             unsigned char* __restrict__ Kf,
                                             unsigned char* __restrict__ Vt) {
  int wave = threadIdx.x >> 6, lane = threadIdx.x & 63;
  int lr = lane & 15, lg = lane >> 4;
  int m0 = blockIdx.y * 64 + wave * 16;
  int j0 = blockIdx.x * 128;

  bf16x8 a[4];
#pragma unroll
  for (int ks = 0; ks < 4; ++ks)
    a[ks] = *reinterpret_cast<const bf16x8*>(xb + (size_t)(m0 + lr) * 128 + ks * 32 + lg * 8);

  f32x4 acc[8];
#pragma unroll
  for (int nf = 0; nf < 8; ++nf) acc[nf] = (f32x4){0.f, 0.f, 0.f, 0.f};

#pragma unroll
  for (int ks = 0; ks < 4; ++ks) {
#pragma unroll
    for (int nf = 0; nf < 8; ++nf) {
      bf16x8 bfr = *reinterpret_cast<const bf16x8*>(
          wqt + (size_t)(j0 + nf * 16 + lr) * 128 + ks * 32 + lg * 8);
      acc[nf] = __builtin_amdgcn_mfma_f32_16x16x32_bf16(a[ks], bfr, acc[nf], 0, 0, 0);
    }
  }

  int bb = m0 >> 11;            // whole 16-row group is in one batch (2048%16==0)
  int sbase = m0 & 2047;
#pragma unroll
  for (int nf = 0; nf < 8; ++nf) {
    int j = j0 + nf * 16 + lr;
    float bv = bias[j];
    int sel = j >> 10;
    int jj = j & 1023;
    int h = jj >> 7, c = jj & 127;
    size_t bh = (size_t)(bb * NHEAD + h);
    if (sel == 2) {
      unsigned w = 0;
#pragma unroll
      for (int r = 0; r < 4; ++r)
        w |= f2e4m3((acc[nf][r] + bv) * 16.0f) << (8 * r);
      *reinterpret_cast<unsigned*>(Vt + (bh * HDIM + c) * SEQ + sbase + lg * 4) = w;
    } else {
      unsigned char* dst = (sel ? Kf : Qf);
#pragma unroll
      for (int r = 0; r < 4; ++r) {
        int s = sbase + lg * 4 + r;
        dst[(bh * SEQ + s) * HDIM + c] = (unsigned char)f2e4m3((acc[nf][r] + bv) * 4.0f);
      }
    }
  }
}

// ---------------- 5) Tot8[bh][c] = 0.125 * sum_t V = sum_t decode(Vf)/128 ------
__global__ __launch_bounds__(256) void k_tot(const unsigned char* __restrict__ Vt,
                                             float* __restrict__ Tot8) {
  __shared__ float lut[256];
  {
    int t = threadIdx.x;
    unsigned e = (t >> 3) & 15u, m = t & 7u;
    float mag = e ? ldexpf((float)(8 + m), (int)e - 10) : ldexpf((float)m, -9);
    lut[t] = (t & 128) ? -mag : mag;
  }
  __syncthreads();
  int wave = threadIdx.x >> 6, lane = threadIdx.x & 63;
  int row = blockIdx.x * 4 + wave;
  const unsigned char* p = Vt + (size_t)row * SEQ;
  float s = 0.f;
#pragma unroll
  for (int k = 0; k < 4; ++k) {
    u64 v = *reinterpret_cast<const u64*>(p + k * 512 + lane * 8);
#pragma unroll
    for (int j = 0; j < 8; ++j) s += lut[(unsigned)(v >> (8 * j)) & 255u];
  }
#pragma unroll
  for (int off = 32; off > 0; off >>= 1) s += __shfl_down(s, off, 64);
  if (lane == 0) Tot8[row] = s * 0.0078125f;
}

// ---------------- 6) Attention (fp8), R=64 rows/block, tc-split partials -------
// 256 blocks x 512 thr. Logical id L (XCD-chunk swizzled): p=L&15, tc=(L>>4)&3,
// b=L>>6. Block processes chunks {p, 31-p} sequentially (64 rows each), tiles
// tt%4==tc descending. Writes fp8 partial (dev sums / 128) into Part[tc].
__global__ __launch_bounds__(512, 2) void k_attn(const unsigned char* __restrict__ Qf,
                                                 const unsigned char* __restrict__ Kf,
                                                 const unsigned char* __restrict__ Vt,
                                                 unsigned char* __restrict__ Part) {
  __shared__ float Sm[8][64][36];          // raw QK^T (x16 scaled), f32
  __shared__ unsigned char Pm[8][64][48];  // P8 = 8*(alpha-1/8) fp8

  int tid = threadIdx.x;
  int h = tid >> 6, lane = tid & 63, lr = lane & 15, lg = lane >> 4;
  int bid = blockIdx.x;
  int L = (bid & 7) * 32 + (bid >> 3);     // XCD-chunk swizzle (256%8==0)
  int p = L & 15, tc = (L >> 4) & 3, b = L >> 6;

  const unsigned char* Qh = Qf + ((size_t)(b * NHEAD + h)) * SEQ * HDIM;
  const unsigned char* Kh = Kf + ((size_t)(b * NHEAD + h)) * SEQ * HDIM;
  const unsigned char* Vh = Vt + ((size_t)(b * NHEAD + h)) * HDIM * SEQ;
  unsigned char* PartT = Part + (size_t)tc * (size_t)(4 * SEQ) * 1024;

  int sl = tid >> 3;             // softmax row 0..63
  int t4 = (tid & 7) * 4;        // softmax col base
  const float SC = 0.001953125f; // 1/(32*16): undo Q*4,K*4 and /sqrt(1024)

#define ATTN_TILE(TT, KC, KN)                                                      \
  do {                                                                             \
    int t0 = (TT) * 32;                                                            \
    i64 vf[8];                                                                     \
    _Pragma("unroll")                                                              \
    for (int cf = 0; cf < 8; ++cf)                                                 \
      vf[cf] = *reinterpret_cast<const i64*>(Vh + (size_t)(cf * 16 + lr) * SEQ + t0 + lg * 8); \
    if ((TT) - 4 >= ttMin) {                                                       \
      int t0n = t0 - 128;                                                          \
      _Pragma("unroll")                                                            \
      for (int nf = 0; nf < 2; ++nf)                                               \
        _Pragma("unroll")                                                          \
        for (int ks = 0; ks < 4; ++ks)                                             \
          KN[nf][ks] = *reinterpret_cast<const i64*>(                              \
              Kh + (size_t)(t0n + nf * 16 + lr) * HDIM + ks * 32 + lg * 8);        \
    }                                                                              \
    _Pragma("unroll")                                                              \
    for (int rf = 0; rf < 4; ++rf) {                                               \
      f32x4 s0v = (f32x4){0.f, 0.f, 0.f, 0.f}, s1v = (f32x4){0.f, 0.f, 0.f, 0.f}; \
      _Pragma("unroll")                                                            \
      for (int ks = 0; ks < 4; ++ks) {                                             \
        s0v = __builtin_amdgcn_mfma_f32_16x16x32_fp8_fp8(qa[rf][ks], KC[0][ks], s0v, 0, 0, 0); \
        s1v = __builtin_amdgcn_mfma_f32_16x16x32_fp8_fp8(qa[rf][ks], KC[1][ks], s1v, 0, 0, 0); \
      }                                                                            \
      int rowb = rf * 16 + lg * 4;                                                 \
      _Pragma("unroll")                                                            \
      for (int r = 0; r < 4; ++r) {                                                \
        Sm[h][rowb + r][lr] = s0v[r];                                              \
        Sm[h][rowb + r][16 + lr] = s1v[r];                                         \
      }                                                                            \
    }                                                                              \
    __syncthreads();                                                               \
    {                                                                              \
      int sg = rb + sl;                                                            \
      int tg = t0 + t4;                                                            \
      float e[8][4];                                                               \
      float sm0 = 0.f, sm1 = 0.f, sm2 = 0.f, sm3 = 0.f;                            \
      _Pragma("unroll")                                                            \
      for (int hh = 0; hh < 8; ++hh) {                                             \
        float4 v = *reinterpret_cast<const float4*>(&Sm[hh][sl][t4]);              \
        e[hh][0] = __expf(v.x * SC); sm0 += e[hh][0];                              \
        e[hh][1] = __expf(v.y * SC); sm1 += e[hh][1];                              \
        e[hh][2] = __expf(v.z * SC); sm2 += e[hh][2];                              \
        e[hh][3] = __expf(v.w * SC); sm3 += e[hh][3];                              \
      }                                                                            \
      float inv[4] = {1.0f / sm0, 1.0f / sm1, 1.0f / sm2, 1.0f / sm3};             \
      _Pragma("unroll")                                                            \
      for (int hh = 0; hh < 8; ++hh) {                                             \
        unsigned w = 0;                                                            \
        _Pragma("unroll")                                                          \
        for (int j = 0; j < 4; ++j)                                                \
          if (tg + j >= sg) {                                                      \
            float av = e[hh][j] * inv[j] - 0.125f;                                 \
            w |= f2e4m3(av * 8.0f) << (8 * j);                                     \
          }                                                                        \
        *reinterpret_cast<unsigned*>(&Pm[hh][sl][t4]) = w;                         \
      }                                                                            \
    }                                                                              \
    __syncthreads();                                                               \
    _Pragma("unroll")                                                              \
    for (int rf = 0; rf < 4; ++rf) {                                               \
      i64 pa = *reinterpret_cast<const i64*>(&Pm[h][rf * 16 + lr][lg * 8]);        \
      _Pragma("unroll")                                                            \
      for (int cf = 0; cf < 8; ++cf)                                               \
        oa[rf][cf] = __builtin_amdgcn_mfma_f32_16x16x32_fp8_fp8(pa, vf[cf], oa[rf][cf], 0, 0, 0); \
    }                                                                              \
  } while (0)

#pragma unroll 1
  for (int ph = 0; ph < 2; ++ph) {
    int c0 = ph ? (31 - p) : p;
    int rb = c0 * 64;

    i64 qa[4][4];
#pragma unroll
    for (int rf = 0; rf < 4; ++rf)
#pragma unroll
      for (int ks = 0; ks < 4; ++ks)
        qa[rf][ks] = *reinterpret_cast<const i64*>(
            Qh + (size_t)(rb + rf * 16 + lr) * HDIM + ks * 32 + lg * 8);

    f32x4 oa[4][8];
#pragma unroll
    for (int rf = 0; rf < 4; ++rf)
#pragma unroll
      for (int cf = 0; cf < 8; ++cf) oa[rf][cf] = (f32x4){0.f, 0.f, 0.f, 0.f};

    int ttF = 60 + tc, ttMin = 2 * c0;
    i64 kfA[2][4], kfB[2][4];
    if (ttF >= ttMin) {
      int t0 = ttF * 32;
#pragma unroll
      for (int nf = 0; nf < 2; ++nf)
#pragma unroll
        for (int ks = 0; ks < 4; ++ks)
          kfA[nf][ks] = *reinterpret_cast<const i64*>(
              Kh + (size_t)(t0 + nf * 16 + lr) * HDIM + ks * 32 + lg * 8);
#pragma unroll 1
      for (int tt = ttF; tt >= ttMin; tt -= 8) {
        ATTN_TILE(tt, kfA, kfB);
        if (tt - 4 >= ttMin) ATTN_TILE(tt - 4, kfB, kfA);
      }
    }

    // flush partial (dev/128) as fp8 — unconditional so every element is written
    unsigned char* baseP = PartT + (size_t)(b * SEQ + rb) * 1024 + h * HDIM;
#pragma unroll
    for (int rf = 0; rf < 4; ++rf)
#pragma unroll
      for (int cf = 0; cf < 8; ++cf)
#pragma unroll
        for (int r = 0; r < 4; ++r)
          baseP[(size_t)(rf * 16 + lg * 4 + r) * 1024 + cf * 16 + lr] =
              (unsigned char)f2e4m3(oa[rf][cf][r] * 0.0078125f);
  }
#undef ATTN_TILE
}

// ---------------- 7) Output GEMM: (sum_tc Part + Tot8) @ Wot^T + b_o -> fp32 ---
__global__ __launch_bounds__(256) void k_out(const unsigned char* __restrict__ Part,
                                             const float* __restrict__ Tot8,
                                             const short* __restrict__ wot,
                                             const float* __restrict__ bo,
                                             float* __restrict__ out) {
  __shared__ float lut[256];
  {
    int t = threadIdx.x;
    unsigned e = (t >> 3) & 15u, m = t & 7u;
    float mag = e ? ldexpf((float)(8 + m), (int)e - 10) : ldexpf((float)m, -9);
    lut[t] = (t & 128) ? -mag : mag;
  }
  __syncthreads();

  const size_t PSZ = (size_t)(4 * SEQ) * 1024;
  int wave = threadIdx.x >> 6, lane = threadIdx.x & 63;
  int lr = lane & 15, lg = lane >> 4;
  int m0 = blockIdx.x * 64 + wave * 16;
  int bb = m0 >> 11;
  const float* t8 = Tot8 + ((size_t)bb << 10);

  f32x4 acc[8];
#pragma unroll
  for (int nf = 0; nf < 8; ++nf) acc[nf] = (f32x4){0.f, 0.f, 0.f, 0.f};

  for (int ks = 0; ks < 32; ++ks) {
    int kb = ks * 32 + lg * 8;
    const unsigned char* pr = Part + (size_t)(m0 + lr) * 1024 + kb;
    u64 q0 = *reinterpret_cast<const u64*>(pr);
    u64 q1 = *reinterpret_cast<const u64*>(pr + PSZ);
    u64 q2 = *reinterpret_cast<const u64*>(pr + 2 * PSZ);
    u64 q3 = *reinterpret_cast<const u64*>(pr + 3 * PSZ);
    float4 ta = *reinterpret_cast<const float4*>(t8 + kb);
    float4 tb = *reinterpret_cast<const float4*>(t8 + kb + 4);
    float tv[8] = {ta.x, ta.y, ta.z, ta.w, tb.x, tb.y, tb.z, tb.w};
    bf16x8 af;
#pragma unroll
    for (int j = 0; j < 8; ++j) {
      float f = lut[(unsigned)(q0 >> (8 * j)) & 255u] +
                lut[(unsigned)(q1 >> (8 * j)) & 255u] +
                lut[(unsigned)(q2 >> (8 * j)) & 255u] +
                lut[(unsigned)(q3 >> (8 * j)) & 255u] + tv[j];
      af[j] = f2b(f);
    }
#pragma unroll
    for (int nf = 0; nf < 8; ++nf) {
      bf16x8 bfr = *reinterpret_cast<const bf16x8*>(
          wot + (size_t)(nf * 16 + lr) * 1024 + ks * 32 + lg * 8);
      acc[nf] = __builtin_amdgcn_mfma_f32_16x16x32_bf16(af, bfr, acc[nf], 0, 0, 0);
    }
  }
#pragma unroll
  for (int nf = 0; nf < 8; ++nf) {
    int c = nf * 16 + lr;
    float bv = bo[c];
#pragma unroll
    for (int r = 0; r < 4; ++r)
      out[(size_t)(m0 + lg * 4 + r) * 128 + c] = acc[nf][r] + bv;
  }
}

extern "C" void kernel_launch(void* const* d_in, const int* in_sizes, int n_in,
                              void* d_out, int out_size, void* d_ws, size_t ws_size,
                              hipStream_t stream) {
  const float* x    = (const float*)d_in[0];
  const float* wqkv = (const float*)d_in[1];
  const float* bqkv = (const float*)d_in[2];
  const float* wo   = (const float*)d_in[3];
  const float* bo   = (const float*)d_in[4];

  char* ws = (char*)d_ws;
  const size_t MB = (size_t)1 << 20;
  short* xb          = (short*)(ws + 0);          //  2 MB : x bf16
  short* wqt         = (short*)(ws + 2 * MB);     // .75MB : W_qkv^T bf16
  short* wot         = (short*)(ws + 3 * MB);     // .25MB : W_o^T bf16
  unsigned char* Qf  = (unsigned char*)(ws + 4 * MB);   // 8 MB fp8 [bh][s][c]
  unsigned char* Kf  = (unsigned char*)(ws + 12 * MB);  // 8 MB fp8 [bh][t][c]
  unsigned char* Vt  = (unsigned char*)(ws + 20 * MB);  // 8 MB fp8 [bh][c][t]
  float* Tot8        = (float*)(ws + 28 * MB);          // 16 KB
  unsigned char* Part = (unsigned char*)(ws + 29 * MB); // 32 MB fp8 x4 partials

  hipLaunchKernelGGL(k_cvt_x, dim3(512), dim3(256), 0, stream, x, xb);
  hipLaunchKernelGGL(k_wqkv, dim3(1536), dim3(256), 0, stream, wqkv, wqt);
  hipLaunchKernelGGL(k_wo, dim3(512), dim3(256), 0, stream, wo, wot);
  hipLaunchKernelGGL(k_qkv, dim3(24, 128), dim3(256), 0, stream, xb, wqt, bqkv, Qf, Kf, Vt);
  hipLaunchKernelGGL(k_tot, dim3(1024), dim3(256), 0, stream, Vt, Tot8);
  hipLaunchKernelGGL(k_attn, dim3(256), dim3(512), 0, stream, Qf, Kf, Vt, Part);
  hipLaunchKernelGGL(k_out, dim3(128), dim3(256), 0, stream, Part, Tot8, wot, bo, (float*)d_out);
}

// Round 3
// 266.149 us; speedup vs baseline: 1.8415x; 1.4067x over previous
//
#include <hip/hip_runtime.h>
#include <hip/hip_bf16.h>

// Problem constants: B=4, S=2048, HID=128, NH=8, D_MODEL=1024
#define SEQ 2048
#define NHEAD 8
#define HDIM 128

typedef __attribute__((ext_vector_type(8))) short bf16x8;
typedef __attribute__((ext_vector_type(4))) float f32x4;
typedef long i64;
typedef unsigned long long u64;

static __device__ __forceinline__ short f2b(float f) {
  union { float f; unsigned u; } v; v.f = f;
  unsigned r = (v.u + 0x7FFFu + ((v.u >> 16) & 1u)) >> 16;
  return (short)(unsigned short)r;
}
static __device__ __forceinline__ float b2f(short b) {
  union { unsigned u; float f; } v; v.u = ((unsigned)(unsigned short)b) << 16;
  return v.f;
}
// OCP e4m3fn encode, RTN-even for normals, denorms handled, saturate at 448.
static __device__ __forceinline__ unsigned f2e4m3(float x) {
  union { float f; unsigned u; } v; v.f = x;
  unsigned s = (v.u >> 24) & 0x80u;
  unsigned a = v.u & 0x7FFFFFFFu;
  if (a > 0x43E00000u) a = 0x43E00000u;      // clamp |x| to 448
  if (a < 0x3C800000u) {                     // |x| < 2^-6 : denormal domain
    union { unsigned u; float f; } w; w.u = a;
    return s | (unsigned)(int)(w.f * 512.0f + 0.5f);
  }
  a += 0x7FFFFu + ((a >> 20) & 1u);          // round to 3 mantissa bits
  return s | (((a >> 23) - 120u) << 3) | ((a >> 20) & 7u);
}

// ---------------- 1) x fp32 -> bf16 ----------------
__global__ __launch_bounds__(256) void k_cvt_x(const float* __restrict__ x,
                                               short* __restrict__ xb) {
  int i = blockIdx.x * blockDim.x + threadIdx.x;
  const float4* p = reinterpret_cast<const float4*>(x) + (size_t)i * 2;
  float4 a = p[0], c = p[1];
  bf16x8 o;
  o[0] = f2b(a.x); o[1] = f2b(a.y); o[2] = f2b(a.z); o[3] = f2b(a.w);
  o[4] = f2b(c.x); o[5] = f2b(c.y); o[6] = f2b(c.z); o[7] = f2b(c.w);
  reinterpret_cast<bf16x8*>(xb)[i] = o;
}

// ---------------- 2) W_qkv [128][3072] -> Wqt bf16 [3072][128] ----------------
__global__ __launch_bounds__(256) void k_wqkv(const float* __restrict__ w,
                                              short* __restrict__ wt) {
  int tid = blockIdx.x * blockDim.x + threadIdx.x;
  int k = tid & 127, j = tid >> 7;
  wt[tid] = f2b(w[(size_t)k * 3072 + j]);
}

// ---------------- 3) W_o [1024][128] -> Wot bf16 [128][1024] ----------------
__global__ __launch_bounds__(256) void k_wo(const float* __restrict__ w,
                                            short* __restrict__ wt) {
  int tid = blockIdx.x * blockDim.x + threadIdx.x;
  int k = tid & 1023, c = tid >> 10;
  wt[tid] = f2b(w[(size_t)k * 128 + c]);
}

// ---------------- 4) QKV GEMM -> Qf,Kf fp8 [bh][s][c]; Vt fp8 [bh][c][t] -------
// Scales: Q*4, K*4, V*16 (decoded later). V written pre-transposed.
__global__ __launch_bounds__(256) void k_qkv(const short* __restrict__ xb,
                                             const short* __restrict__ wqt,
                                             const float* __restrict__ bias,
                                             unsigned char* __restrict__ Qf,
                                             unsigned char* __restrict__ Kf,
                                             unsigned char* __restrict__ Vt) {
  int wave = threadIdx.x >> 6, lane = threadIdx.x & 63;
  int lr = lane & 15, lg = lane >> 4;
  int m0 = blockIdx.y * 64 + wave * 16;
  int j0 = blockIdx.x * 128;

  bf16x8 a[4];
#pragma unroll
  for (int ks = 0; ks < 4; ++ks)
    a[ks] = *reinterpret_cast<const bf16x8*>(xb + (size_t)(m0 + lr) * 128 + ks * 32 + lg * 8);

  f32x4 acc[8];
#pragma unroll
  for (int nf = 0; nf < 8; ++nf) acc[nf] = (f32x4){0.f, 0.f, 0.f, 0.f};

#pragma unroll
  for (int ks = 0; ks < 4; ++ks) {
#pragma unroll
    for (int nf = 0; nf < 8; ++nf) {
      bf16x8 bfr = *reinterpret_cast<const bf16x8*>(
          wqt + (size_t)(j0 + nf * 16 + lr) * 128 + ks * 32 + lg * 8);
      acc[nf] = __builtin_amdgcn_mfma_f32_16x16x32_bf16(a[ks], bfr, acc[nf], 0, 0, 0);
    }
  }

  int bb = m0 >> 11;
  int sbase = m0 & 2047;
#pragma unroll
  for (int nf = 0; nf < 8; ++nf) {
    int j = j0 + nf * 16 + lr;
    float bv = bias[j];
    int sel = j >> 10;
    int jj = j & 1023;
    int h = jj >> 7, c = jj & 127;
    size_t bh = (size_t)(bb * NHEAD + h);
    if (sel == 2) {
      unsigned w = 0;
#pragma unroll
      for (int r = 0; r < 4; ++r)
        w |= f2e4m3((acc[nf][r] + bv) * 16.0f) << (8 * r);
      *reinterpret_cast<unsigned*>(Vt + (bh * HDIM + c) * SEQ + sbase + lg * 4) = w;
    } else {
      unsigned char* dst = (sel ? Kf : Qf);
#pragma unroll
      for (int r = 0; r < 4; ++r) {
        int s = sbase + lg * 4 + r;
        dst[(bh * SEQ + s) * HDIM + c] = (unsigned char)f2e4m3((acc[nf][r] + bv) * 4.0f);
      }
    }
  }
}

// ---------------- 5) Tot8[bh][c] = 0.125 * sum_t V ------
__global__ __launch_bounds__(256) void k_tot(const unsigned char* __restrict__ Vt,
                                             float* __restrict__ Tot8) {
  __shared__ float lut[256];
  {
    int t = threadIdx.x;
    unsigned e = (t >> 3) & 15u, m = t & 7u;
    float mag = e ? ldexpf((float)(8 + m), (int)e - 10) : ldexpf((float)m, -9);
    lut[t] = (t & 128) ? -mag : mag;
  }
  __syncthreads();
  int wave = threadIdx.x >> 6, lane = threadIdx.x & 63;
  int row = blockIdx.x * 4 + wave;
  const unsigned char* p = Vt + (size_t)row * SEQ;
  float s = 0.f;
#pragma unroll
  for (int k = 0; k < 4; ++k) {
    u64 v = *reinterpret_cast<const u64*>(p + k * 512 + lane * 8);
#pragma unroll
    for (int j = 0; j < 8; ++j) s += lut[(unsigned)(v >> (8 * j)) & 255u];
  }
#pragma unroll
  for (int off = 32; off > 0; off >>= 1) s += __shfl_down(s, off, 64);
  if (lane == 0) Tot8[row] = s * 0.0078125f;
}

// ---------------- 6) Attention (fp8), 32 rows/phase, tc-split=2, bf16 partials -
// 256 blocks x 512 thr. L = XCD-chunk swizzle: p=L&31, tc=(L>>5)&1, b=L>>6.
// Block: chunks {p, 63-p} (32 rows) sequentially; tiles tt ≡ tc (mod 2), desc.
// Regs: oa 64 + qa 16 + kf 32 + vf 16 + sm 16 + temps ≈ 190 < 256 (no spills).
__global__ __launch_bounds__(512, 2) void k_attn(const unsigned char* __restrict__ Qf,
                                                 const unsigned char* __restrict__ Kf,
                                                 const unsigned char* __restrict__ Vt,
                                                 short* __restrict__ Part) {
  __shared__ float Sm[8][32][36];          // raw QK^T (x16 scaled), f32  (36 KB)
  __shared__ unsigned char Pm[8][32][40];  // P8 = 8*(alpha-1/8) fp8      (10 KB)

  int tid = threadIdx.x;
  int h = tid >> 6, lane = tid & 63, lr = lane & 15, lg = lane >> 4;
  int bid = blockIdx.x;
  int L = (bid & 7) * 32 + (bid >> 3);     // XCD-chunk swizzle (256%8==0)
  int p = L & 31, tc = (L >> 5) & 1, b = L >> 6;

  const unsigned char* Qh = Qf + ((size_t)(b * NHEAD + h)) * SEQ * HDIM;
  const unsigned char* Kh = Kf + ((size_t)(b * NHEAD + h)) * SEQ * HDIM;
  const unsigned char* Vh = Vt + ((size_t)(b * NHEAD + h)) * HDIM * SEQ;
  short* PartT = Part + (size_t)tc * (size_t)(4 * SEQ) * 1024;

  int sl = tid >> 4;             // softmax row 0..31
  int t2 = (tid & 15) * 2;       // softmax col base (2 cols/thread)
  const float SC = 0.001953125f; // 1/(32*16): undo Q*4,K*4 and /sqrt(1024)

#define ATTN_TILE(TT, KC, KN)                                                      \
  do {                                                                             \
    int t0 = (TT) * 32;                                                            \
    i64 vf[8];                                                                     \
    _Pragma("unroll")                                                              \
    for (int cf = 0; cf < 8; ++cf)                                                 \
      vf[cf] = *reinterpret_cast<const i64*>(Vh + (size_t)(cf * 16 + lr) * SEQ + t0 + lg * 8); \
    if ((TT) - 2 >= ttMin) {                                                       \
      int t0n = t0 - 64;                                                           \
      _Pragma("unroll")                                                            \
      for (int nf = 0; nf < 2; ++nf)                                               \
        _Pragma("unroll")                                                          \
        for (int ks = 0; ks < 4; ++ks)                                             \
          KN[nf][ks] = *reinterpret_cast<const i64*>(                              \
              Kh + (size_t)(t0n + nf * 16 + lr) * HDIM + ks * 32 + lg * 8);        \
    }                                                                              \
    _Pragma("unroll")                                                              \
    for (int rf = 0; rf < 2; ++rf) {                                               \
      f32x4 s0v = (f32x4){0.f, 0.f, 0.f, 0.f}, s1v = (f32x4){0.f, 0.f, 0.f, 0.f}; \
      _Pragma("unroll")                                                            \
      for (int ks = 0; ks < 4; ++ks) {                                             \
        s0v = __builtin_amdgcn_mfma_f32_16x16x32_fp8_fp8(qa[rf][ks], KC[0][ks], s0v, 0, 0, 0); \
        s1v = __builtin_amdgcn_mfma_f32_16x16x32_fp8_fp8(qa[rf][ks], KC[1][ks], s1v, 0, 0, 0); \
      }                                                                            \
      int rowb = rf * 16 + lg * 4;                                                 \
      _Pragma("unroll")                                                            \
      for (int r = 0; r < 4; ++r) {                                                \
        Sm[h][rowb + r][lr] = s0v[r];                                              \
        Sm[h][rowb + r][16 + lr] = s1v[r];                                         \
      }                                                                            \
    }                                                                              \
    __syncthreads();                                                               \
    {                                                                              \
      int sg = rb + sl;                                                            \
      int tg = t0 + t2;                                                            \
      float e[8][2];                                                               \
      float sm0 = 0.f, sm1 = 0.f;                                                  \
      _Pragma("unroll")                                                            \
      for (int hh = 0; hh < 8; ++hh) {                                             \
        float2 v = *reinterpret_cast<const float2*>(&Sm[hh][sl][t2]);              \
        e[hh][0] = __expf(v.x * SC); sm0 += e[hh][0];                              \
        e[hh][1] = __expf(v.y * SC); sm1 += e[hh][1];                              \
      }                                                                            \
      float inv0 = 1.0f / sm0, inv1 = 1.0f / sm1;                                  \
      _Pragma("unroll")                                                            \
      for (int hh = 0; hh < 8; ++hh) {                                             \
        unsigned w = 0;                                                            \
        if (tg >= sg)     w |= f2e4m3((e[hh][0] * inv0 - 0.125f) * 8.0f);          \
        if (tg + 1 >= sg) w |= f2e4m3((e[hh][1] * inv1 - 0.125f) * 8.0f) << 8;     \
        *reinterpret_cast<unsigned short*>(&Pm[hh][sl][t2]) = (unsigned short)w;   \
      }                                                                            \
    }                                                                              \
    __syncthreads();                                                               \
    _Pragma("unroll")                                                              \
    for (int rf = 0; rf < 2; ++rf) {                                               \
      i64 pa = *reinterpret_cast<const i64*>(&Pm[h][rf * 16 + lr][lg * 8]);        \
      _Pragma("unroll")                                                            \
      for (int cf = 0; cf < 8; ++cf)                                               \
        oa[rf][cf] = __builtin_amdgcn_mfma_f32_16x16x32_fp8_fp8(pa, vf[cf], oa[rf][cf], 0, 0, 0); \
    }                                                                              \
  } while (0)

#pragma unroll 1
  for (int ph = 0; ph < 2; ++ph) {
    int c0 = ph ? (63 - p) : p;
    int rb = c0 * 32;

    i64 qa[2][4];
#pragma unroll
    for (int rf = 0; rf < 2; ++rf)
#pragma unroll
      for (int ks = 0; ks < 4; ++ks)
        qa[rf][ks] = *reinterpret_cast<const i64*>(
            Qh + (size_t)(rb + rf * 16 + lr) * HDIM + ks * 32 + lg * 8);

    f32x4 oa[2][8];
#pragma unroll
    for (int rf = 0; rf < 2; ++rf)
#pragma unroll
      for (int cf = 0; cf < 8; ++cf) oa[rf][cf] = (f32x4){0.f, 0.f, 0.f, 0.f};

    int ttF = 62 + tc, ttMin = c0;
    i64 kfA[2][4], kfB[2][4];
    if (ttF >= ttMin) {
      int t0 = ttF * 32;
#pragma unroll
      for (int nf = 0; nf < 2; ++nf)
#pragma unroll
        for (int ks = 0; ks < 4; ++ks)
          kfA[nf][ks] = *reinterpret_cast<const i64*>(
              Kh + (size_t)(t0 + nf * 16 + lr) * HDIM + ks * 32 + lg * 8);
#pragma unroll 1
      for (int tt = ttF; tt >= ttMin; tt -= 4) {
        ATTN_TILE(tt, kfA, kfB);
        if (tt - 2 >= ttMin) ATTN_TILE(tt - 2, kfB, kfA);
      }
    }

    // flush partial (dev = oa/128) as bf16 — unconditional, covers all rows
    short* baseP = PartT + (size_t)(b * SEQ + rb) * 1024 + h * HDIM;
#pragma unroll
    for (int rf = 0; rf < 2; ++rf)
#pragma unroll
      for (int cf = 0; cf < 8; ++cf)
#pragma unroll
        for (int r = 0; r < 4; ++r)
          baseP[(size_t)(rf * 16 + lg * 4 + r) * 1024 + cf * 16 + lr] =
              f2b(oa[rf][cf][r] * 0.0078125f);
  }
#undef ATTN_TILE
}

// ---------------- 7) Output GEMM: (Part0 + Part1 + Tot8) @ Wot^T + b_o -> fp32 -
// 256 blocks x 256 thr; block = 32 rows; wave (w&1)=row half, (w>>1)=col half.
__global__ __launch_bounds__(256) void k_out(const short* __restrict__ Part,
                                             const float* __restrict__ Tot8,
                                             const short* __restrict__ wot,
                                             const float* __restrict__ bo,
                                             float* __restrict__ out) {
  const size_t PSZ = (size_t)(4 * SEQ) * 1024;
  int wave = threadIdx.x >> 6, lane = threadIdx.x & 63;
  int lr = lane & 15, lg = lane >> 4;
  int m0 = blockIdx.x * 32 + (wave & 1) * 16;
  int n0 = (wave >> 1) * 64;
  int bb = m0 >> 11;
  const float* t8 = Tot8 + ((size_t)bb << 10);

  f32x4 acc[4];
#pragma unroll
  for (int nf = 0; nf < 4; ++nf) acc[nf] = (f32x4){0.f, 0.f, 0.f, 0.f};

  for (int ks = 0; ks < 32; ++ks) {
    int kb = ks * 32 + lg * 8;
    const short* pr = Part + (size_t)(m0 + lr) * 1024 + kb;
    bf16x8 q0 = *reinterpret_cast<const bf16x8*>(pr);
    bf16x8 q1 = *reinterpret_cast<const bf16x8*>(pr + PSZ);
    float4 ta = *reinterpret_cast<const float4*>(t8 + kb);
    float4 tb = *reinterpret_cast<const float4*>(t8 + kb + 4);
    float tv[8] = {ta.x, ta.y, ta.z, ta.w, tb.x, tb.y, tb.z, tb.w};
    bf16x8 af;
#pragma unroll
    for (int j = 0; j < 8; ++j)
      af[j] = f2b(b2f(q0[j]) + b2f(q1[j]) + tv[j]);
#pragma unroll
    for (int nf = 0; nf < 4; ++nf) {
      bf16x8 bfr = *reinterpret_cast<const bf16x8*>(
          wot + (size_t)(n0 + nf * 16 + lr) * 1024 + kb);
      acc[nf] = __builtin_amdgcn_mfma_f32_16x16x32_bf16(af, bfr, acc[nf], 0, 0, 0);
    }
  }
#pragma unroll
  for (int nf = 0; nf < 4; ++nf) {
    int c = n0 + nf * 16 + lr;
    float bv = bo[c];
#pragma unroll
    for (int r = 0; r < 4; ++r)
      out[(size_t)(m0 + lg * 4 + r) * 128 + c] = acc[nf][r] + bv;
  }
}

extern "C" void kernel_launch(void* const* d_in, const int* in_sizes, int n_in,
                              void* d_out, int out_size, void* d_ws, size_t ws_size,
                              hipStream_t stream) {
  const float* x    = (const float*)d_in[0];
  const float* wqkv = (const float*)d_in[1];
  const float* bqkv = (const float*)d_in[2];
  const float* wo   = (const float*)d_in[3];
  const float* bo   = (const float*)d_in[4];

  char* ws = (char*)d_ws;
  const size_t MB = (size_t)1 << 20;
  short* xb          = (short*)(ws + 0);          //  2 MB : x bf16
  short* wqt         = (short*)(ws + 2 * MB);     // .75MB : W_qkv^T bf16
  short* wot         = (short*)(ws + 3 * MB);     // .25MB : W_o^T bf16
  unsigned char* Qf  = (unsigned char*)(ws + 4 * MB);   // 8 MB fp8 [bh][s][c]
  unsigned char* Kf  = (unsigned char*)(ws + 12 * MB);  // 8 MB fp8 [bh][t][c]
  unsigned char* Vt  = (unsigned char*)(ws + 20 * MB);  // 8 MB fp8 [bh][c][t]
  float* Tot8        = (float*)(ws + 28 * MB);          // 16 KB
  short* Part        = (short*)(ws + 29 * MB);          // 32 MB bf16 x2 partials

  hipLaunchKernelGGL(k_cvt_x, dim3(512), dim3(256), 0, stream, x, xb);
  hipLaunchKernelGGL(k_wqkv, dim3(1536), dim3(256), 0, stream, wqkv, wqt);
  hipLaunchKernelGGL(k_wo, dim3(512), dim3(256), 0, stream, wo, wot);
  hipLaunchKernelGGL(k_qkv, dim3(24, 128), dim3(256), 0, stream, xb, wqt, bqkv, Qf, Kf, Vt);
  hipLaunchKernelGGL(k_tot, dim3(1024), dim3(256), 0, stream, Vt, Tot8);
  hipLaunchKernelGGL(k_attn, dim3(256), dim3(512), 0, stream, Qf, Kf, Vt, Part);
  hipLaunchKernelGGL(k_out, dim3(256), dim3(256), 0, stream, Part, Tot8, wot, bo, (float*)d_out);
}

// Round 4
// 262.328 us; speedup vs baseline: 1.8683x; 1.0146x over previous
//
#include <hip/hip_runtime.h>
#include <hip/hip_bf16.h>

// Problem constants: B=4, S=2048, HID=128, NH=8, D_MODEL=1024
#define SEQ 2048
#define NHEAD 8
#define HDIM 128

typedef __attribute__((ext_vector_type(8))) short bf16x8;
typedef __attribute__((ext_vector_type(4))) float f32x4;
typedef long i64;
typedef unsigned long long u64;

static __device__ __forceinline__ short f2b(float f) {
  union { float f; unsigned u; } v; v.f = f;
  unsigned r = (v.u + 0x7FFFu + ((v.u >> 16) & 1u)) >> 16;
  return (short)(unsigned short)r;
}
static __device__ __forceinline__ float b2f(short b) {
  union { unsigned u; float f; } v; v.u = ((unsigned)(unsigned short)b) << 16;
  return v.f;
}
// OCP e4m3fn encode (software fallback), RTN-even, saturate at 448.
static __device__ __forceinline__ unsigned f2e4m3(float x) {
  union { float f; unsigned u; } v; v.f = x;
  unsigned s = (v.u >> 24) & 0x80u;
  unsigned a = v.u & 0x7FFFFFFFu;
  if (a > 0x43E00000u) a = 0x43E00000u;
  if (a < 0x3C800000u) {
    union { unsigned u; float f; } w; w.u = a;
    return s | (unsigned)(int)(w.f * 512.0f + 0.5f);
  }
  a += 0x7FFFFu + ((a >> 20) & 1u);
  return s | (((a >> 23) - 120u) << 3) | ((a >> 20) & 7u);
}

#if defined(__has_builtin)
#if __has_builtin(__builtin_amdgcn_cvt_pk_fp8_f32)
#define HAVE_HW_FP8 1
#endif
#endif
// pack 2 floats -> 2 fp8 bytes (low 16 bits)
static __device__ __forceinline__ unsigned cvt_pk_fp8(float a, float b) {
#ifdef HAVE_HW_FP8
  return (unsigned)__builtin_amdgcn_cvt_pk_fp8_f32(a, b, 0, false) & 0xFFFFu;
#else
  return f2e4m3(a) | (f2e4m3(b) << 8);
#endif
}
static __device__ __forceinline__ unsigned cvt_fp8_1(float a) {
  return cvt_pk_fp8(a, 0.0f) & 0xFFu;
}

// ---------------- 1) x fp32 -> bf16 ----------------
__global__ __launch_bounds__(256) void k_cvt_x(const float* __restrict__ x,
                                               short* __restrict__ xb) {
  int i = blockIdx.x * blockDim.x + threadIdx.x;
  const float4* p = reinterpret_cast<const float4*>(x) + (size_t)i * 2;
  float4 a = p[0], c = p[1];
  bf16x8 o;
  o[0] = f2b(a.x); o[1] = f2b(a.y); o[2] = f2b(a.z); o[3] = f2b(a.w);
  o[4] = f2b(c.x); o[5] = f2b(c.y); o[6] = f2b(c.z); o[7] = f2b(c.w);
  reinterpret_cast<bf16x8*>(xb)[i] = o;
}

// ---------------- 2) W_qkv [128][3072] -> Wqt bf16 [3072][128] ----------------
__global__ __launch_bounds__(256) void k_wqkv(const float* __restrict__ w,
                                              short* __restrict__ wt) {
  int tid = blockIdx.x * blockDim.x + threadIdx.x;
  int k = tid & 127, j = tid >> 7;
  wt[tid] = f2b(w[(size_t)k * 3072 + j]);
}

// ---------------- 3) W_o [1024][128] -> Wot bf16 [128][1024] ----------------
__global__ __launch_bounds__(256) void k_wo(const float* __restrict__ w,
                                            short* __restrict__ wt) {
  int tid = blockIdx.x * blockDim.x + threadIdx.x;
  int k = tid & 1023, c = tid >> 10;
  wt[tid] = f2b(w[(size_t)k * 128 + c]);
}

// ---------------- 4) QKV GEMM -> Qf,Kf fp8 [bh][s][c]; Vt fp8 [bh][c][t] -------
__global__ __launch_bounds__(256) void k_qkv(const short* __restrict__ xb,
                                             const short* __restrict__ wqt,
                                             const float* __restrict__ bias,
                                             unsigned char* __restrict__ Qf,
                                             unsigned char* __restrict__ Kf,
                                             unsigned char* __restrict__ Vt) {
  int wave = threadIdx.x >> 6, lane = threadIdx.x & 63;
  int lr = lane & 15, lg = lane >> 4;
  int m0 = blockIdx.y * 64 + wave * 16;
  int j0 = blockIdx.x * 128;

  bf16x8 a[4];
#pragma unroll
  for (int ks = 0; ks < 4; ++ks)
    a[ks] = *reinterpret_cast<const bf16x8*>(xb + (size_t)(m0 + lr) * 128 + ks * 32 + lg * 8);

  f32x4 acc[8];
#pragma unroll
  for (int nf = 0; nf < 8; ++nf) acc[nf] = (f32x4){0.f, 0.f, 0.f, 0.f};

#pragma unroll
  for (int ks = 0; ks < 4; ++ks) {
#pragma unroll
    for (int nf = 0; nf < 8; ++nf) {
      bf16x8 bfr = *reinterpret_cast<const bf16x8*>(
          wqt + (size_t)(j0 + nf * 16 + lr) * 128 + ks * 32 + lg * 8);
      acc[nf] = __builtin_amdgcn_mfma_f32_16x16x32_bf16(a[ks], bfr, acc[nf], 0, 0, 0);
    }
  }

  int bb = m0 >> 11;
  int sbase = m0 & 2047;
#pragma unroll
  for (int nf = 0; nf < 8; ++nf) {
    int j = j0 + nf * 16 + lr;
    float bv = bias[j];
    int sel = j >> 10;
    int jj = j & 1023;
    int h = jj >> 7, c = jj & 127;
    size_t bh = (size_t)(bb * NHEAD + h);
    if (sel == 2) {
      unsigned lo = cvt_pk_fp8((acc[nf][0] + bv) * 16.0f, (acc[nf][1] + bv) * 16.0f);
      unsigned hi = cvt_pk_fp8((acc[nf][2] + bv) * 16.0f, (acc[nf][3] + bv) * 16.0f);
      *reinterpret_cast<unsigned*>(Vt + (bh * HDIM + c) * SEQ + sbase + lg * 4) =
          lo | (hi << 16);
    } else {
      unsigned char* dst = (sel ? Kf : Qf);
#pragma unroll
      for (int r = 0; r < 4; ++r) {
        int s = sbase + lg * 4 + r;
        dst[(bh * SEQ + s) * HDIM + c] = (unsigned char)cvt_fp8_1((acc[nf][r] + bv) * 4.0f);
      }
    }
  }
}

// ---------------- 5) Tot8[bh][c] = 0.125 * sum_t V ------
__global__ __launch_bounds__(256) void k_tot(const unsigned char* __restrict__ Vt,
                                             float* __restrict__ Tot8) {
  __shared__ float lut[256];
  {
    int t = threadIdx.x;
    unsigned e = (t >> 3) & 15u, m = t & 7u;
    float mag = e ? ldexpf((float)(8 + m), (int)e - 10) : ldexpf((float)m, -9);
    lut[t] = (t & 128) ? -mag : mag;
  }
  __syncthreads();
  int wave = threadIdx.x >> 6, lane = threadIdx.x & 63;
  int row = blockIdx.x * 4 + wave;
  const unsigned char* p = Vt + (size_t)row * SEQ;
  float s = 0.f;
#pragma unroll
  for (int k = 0; k < 4; ++k) {
    u64 v = *reinterpret_cast<const u64*>(p + k * 512 + lane * 8);
#pragma unroll
    for (int j = 0; j < 8; ++j) s += lut[(unsigned)(v >> (8 * j)) & 255u];
  }
#pragma unroll
  for (int off = 32; off > 0; off >>= 1) s += __shfl_down(s, off, 64);
  if (lane == 0) Tot8[row] = s * 0.0078125f;
}

// ---------------- 6) Attention (fp8), pipelined: PV(prev) overlaps softmax(cur) -
// 256 blocks x 512 thr. L = XCD-chunk swizzle: p=L&31, tc=(L>>5)&1, b=L>>6.
// Block: chunks {p, 63-p} (32 rows) sequentially; tiles tt ≡ tc (mod 2), desc.
// Per tile: A=[QK->Sm, V/K load issue] bar  B=[PV(prev) MFMA || softmax VALU] bar
__global__ __launch_bounds__(512, 2) void k_attn(const unsigned char* __restrict__ Qf,
                                                 const unsigned char* __restrict__ Kf,
                                                 const unsigned char* __restrict__ Vt,
                                                 short* __restrict__ Part) {
  __shared__ float Sm[8][32][36];             // raw QK^T (x16 scaled), f32 (36 KB)
  __shared__ unsigned char Pm[2][8][32][40];  // P8 double-buffered fp8   (20 KB)

  int tid = threadIdx.x;
  int h = tid >> 6, lane = tid & 63, lr = lane & 15, lg = lane >> 4;
  int bid = blockIdx.x;
  int L = (bid & 7) * 32 + (bid >> 3);     // XCD-chunk swizzle (256%8==0)
  int p = L & 31, tc = (L >> 5) & 1, b = L >> 6;

  const unsigned char* Qh = Qf + ((size_t)(b * NHEAD + h)) * SEQ * HDIM;
  const unsigned char* Kh = Kf + ((size_t)(b * NHEAD + h)) * SEQ * HDIM;
  const unsigned char* Vh = Vt + ((size_t)(b * NHEAD + h)) * HDIM * SEQ;
  short* PartT = Part + (size_t)tc * (size_t)(4 * SEQ) * 1024;

  int sl = tid >> 4;             // softmax row 0..31
  int t2 = (tid & 15) * 2;       // softmax col base (2 cols/thread)
  const float SC = 0.001953125f; // 1/(32*16): undo Q*4,K*4 and /sqrt(1024)

#define ATTN_STEP(TT, KC, KN)                                                      \
  do {                                                                             \
    int t0 = (TT) * 32;                                                            \
    i64 vfC[8];                                                                    \
    _Pragma("unroll")                                                              \
    for (int cf = 0; cf < 8; ++cf)                                                 \
      vfC[cf] = *reinterpret_cast<const i64*>(Vh + (size_t)(cf * 16 + lr) * SEQ + t0 + lg * 8); \
    if ((TT) - 2 >= ttMin) {                                                       \
      int t0n = t0 - 64;                                                           \
      _Pragma("unroll")                                                            \
      for (int nf = 0; nf < 2; ++nf)                                               \
        _Pragma("unroll")                                                          \
        for (int ks = 0; ks < 4; ++ks)                                             \
          KN[nf][ks] = *reinterpret_cast<const i64*>(                              \
              Kh + (size_t)(t0n + nf * 16 + lr) * HDIM + ks * 32 + lg * 8);        \
    }                                                                              \
    _Pragma("unroll")                                                              \
    for (int rf = 0; rf < 2; ++rf) {                                               \
      f32x4 s0v = (f32x4){0.f, 0.f, 0.f, 0.f}, s1v = (f32x4){0.f, 0.f, 0.f, 0.f}; \
      _Pragma("unroll")                                                            \
      for (int ks = 0; ks < 4; ++ks) {                                             \
        s0v = __builtin_amdgcn_mfma_f32_16x16x32_fp8_fp8(qa[rf][ks], KC[0][ks], s0v, 0, 0, 0); \
        s1v = __builtin_amdgcn_mfma_f32_16x16x32_fp8_fp8(qa[rf][ks], KC[1][ks], s1v, 0, 0, 0); \
      }                                                                            \
      int rowb = rf * 16 + lg * 4;                                                 \
      _Pragma("unroll")                                                            \
      for (int r = 0; r < 4; ++r) {                                                \
        Sm[h][rowb + r][lr] = s0v[r];                                              \
        Sm[h][rowb + r][16 + lr] = s1v[r];                                         \
      }                                                                            \
    }                                                                              \
    __syncthreads();                                                               \
    {                                                                              \
      int sg = rb + sl;                                                            \
      int tg = t0 + t2;                                                            \
      float2 sv[8];                                                                \
      _Pragma("unroll")                                                            \
      for (int hh = 0; hh < 8; ++hh)                                               \
        sv[hh] = *reinterpret_cast<const float2*>(&Sm[hh][sl][t2]);                \
      if (havePV) { /* PV(prev): independent MFMA, overlaps softmax VALU */        \
        _Pragma("unroll")                                                          \
        for (int rf = 0; rf < 2; ++rf) {                                           \
          i64 pa = *reinterpret_cast<const i64*>(&Pm[pb ^ 1][h][rf * 16 + lr][lg * 8]); \
          _Pragma("unroll")                                                        \
          for (int cf = 0; cf < 8; ++cf)                                           \
            oa[rf][cf] = __builtin_amdgcn_mfma_f32_16x16x32_fp8_fp8(pa, vfP[cf], oa[rf][cf], 0, 0, 0); \
        }                                                                          \
      }                                                                            \
      float e[8][2];                                                               \
      float sm0 = 0.f, sm1 = 0.f;                                                  \
      _Pragma("unroll")                                                            \
      for (int hh = 0; hh < 8; ++hh) {                                             \
        e[hh][0] = __expf(sv[hh].x * SC); sm0 += e[hh][0];                         \
        e[hh][1] = __expf(sv[hh].y * SC); sm1 += e[hh][1];                         \
      }                                                                            \
      float inv0 = 8.0f / sm0, inv1 = 8.0f / sm1;                                  \
      bool mk0 = (tg >= sg), mk1 = (tg + 1 >= sg);                                 \
      _Pragma("unroll")                                                            \
      for (int hh = 0; hh < 8; ++hh) {                                             \
        float a0 = mk0 ? (e[hh][0] * inv0 - 1.0f) : 0.0f;                          \
        float a1 = mk1 ? (e[hh][1] * inv1 - 1.0f) : 0.0f;                          \
        *reinterpret_cast<unsigned short*>(&Pm[pb][hh][sl][t2]) =                  \
            (unsigned short)cvt_pk_fp8(a0, a1);                                    \
      }                                                                            \
    }                                                                              \
    __syncthreads();                                                               \
    _Pragma("unroll")                                                              \
    for (int cf = 0; cf < 8; ++cf) vfP[cf] = vfC[cf];                              \
    havePV = 1; pb ^= 1;                                                           \
  } while (0)

#pragma unroll 1
  for (int ph = 0; ph < 2; ++ph) {
    int c0 = ph ? (63 - p) : p;
    int rb = c0 * 32;

    i64 qa[2][4];
#pragma unroll
    for (int rf = 0; rf < 2; ++rf)
#pragma unroll
      for (int ks = 0; ks < 4; ++ks)
        qa[rf][ks] = *reinterpret_cast<const i64*>(
            Qh + (size_t)(rb + rf * 16 + lr) * HDIM + ks * 32 + lg * 8);

    f32x4 oa[2][8];
#pragma unroll
    for (int rf = 0; rf < 2; ++rf)
#pragma unroll
      for (int cf = 0; cf < 8; ++cf) oa[rf][cf] = (f32x4){0.f, 0.f, 0.f, 0.f};

    int ttF = 62 + tc, ttMin = c0;
    int havePV = 0, pb = 0;
    i64 vfP[8];
    i64 kfA[2][4], kfB[2][4];
    if (ttF >= ttMin) {
      int t0 = ttF * 32;
#pragma unroll
      for (int nf = 0; nf < 2; ++nf)
#pragma unroll
        for (int ks = 0; ks < 4; ++ks)
          kfA[nf][ks] = *reinterpret_cast<const i64*>(
              Kh + (size_t)(t0 + nf * 16 + lr) * HDIM + ks * 32 + lg * 8);
#pragma unroll 1
      for (int tt = ttF; tt >= ttMin; tt -= 4) {
        ATTN_STEP(tt, kfA, kfB);
        if (tt - 2 >= ttMin) ATTN_STEP(tt - 2, kfB, kfA);
      }
    }
    if (havePV) {  // drain the pending PV
#pragma unroll
      for (int rf = 0; rf < 2; ++rf) {
        i64 pa = *reinterpret_cast<const i64*>(&Pm[pb ^ 1][h][rf * 16 + lr][lg * 8]);
#pragma unroll
        for (int cf = 0; cf < 8; ++cf)
          oa[rf][cf] = __builtin_amdgcn_mfma_f32_16x16x32_fp8_fp8(pa, vfP[cf], oa[rf][cf], 0, 0, 0);
      }
    }

    // flush partial (dev = oa/(128*8)) as bf16 — P was scaled x8
    short* baseP = PartT + (size_t)(b * SEQ + rb) * 1024 + h * HDIM;
#pragma unroll
    for (int rf = 0; rf < 2; ++rf)
#pragma unroll
      for (int cf = 0; cf < 8; ++cf)
#pragma unroll
        for (int r = 0; r < 4; ++r)
          baseP[(size_t)(rf * 16 + lg * 4 + r) * 1024 + cf * 16 + lr] =
              f2b(oa[rf][cf][r] * 0.0009765625f);
  }
#undef ATTN_STEP
}

// ---------------- 7) Output GEMM: (Part0 + Part1 + Tot8) @ Wot^T + b_o -> fp32 -
__global__ __launch_bounds__(256) void k_out(const short* __restrict__ Part,
                                             const float* __restrict__ Tot8,
                                             const short* __restrict__ wot,
                                             const float* __restrict__ bo,
                                             float* __restrict__ out) {
  const size_t PSZ = (size_t)(4 * SEQ) * 1024;
  int wave = threadIdx.x >> 6, lane = threadIdx.x & 63;
  int lr = lane & 15, lg = lane >> 4;
  int m0 = blockIdx.x * 32 + (wave & 1) * 16;
  int n0 = (wave >> 1) * 64;
  int bb = m0 >> 11;
  const float* t8 = Tot8 + ((size_t)bb << 10);

  f32x4 acc[4];
#pragma unroll
  for (int nf = 0; nf < 4; ++nf) acc[nf] = (f32x4){0.f, 0.f, 0.f, 0.f};

  for (int ks = 0; ks < 32; ++ks) {
    int kb = ks * 32 + lg * 8;
    const short* pr = Part + (size_t)(m0 + lr) * 1024 + kb;
    bf16x8 q0 = *reinterpret_cast<const bf16x8*>(pr);
    bf16x8 q1 = *reinterpret_cast<const bf16x8*>(pr + PSZ);
    float4 ta = *reinterpret_cast<const float4*>(t8 + kb);
    float4 tb = *reinterpret_cast<const float4*>(t8 + kb + 4);
    float tv[8] = {ta.x, ta.y, ta.z, ta.w, tb.x, tb.y, tb.z, tb.w};
    bf16x8 af;
#pragma unroll
    for (int j = 0; j < 8; ++j)
      af[j] = f2b(b2f(q0[j]) + b2f(q1[j]) + tv[j]);
#pragma unroll
    for (int nf = 0; nf < 4; ++nf) {
      bf16x8 bfr = *reinterpret_cast<const bf16x8*>(
          wot + (size_t)(n0 + nf * 16 + lr) * 1024 + kb);
      acc[nf] = __builtin_amdgcn_mfma_f32_16x16x32_bf16(af, bfr, acc[nf], 0, 0, 0);
    }
  }
#pragma unroll
  for (int nf = 0; nf < 4; ++nf) {
    int c = n0 + nf * 16 + lr;
    float bv = bo[c];
#pragma unroll
    for (int r = 0; r < 4; ++r)
      out[(size_t)(m0 + lg * 4 + r) * 128 + c] = acc[nf][r] + bv;
  }
}

extern "C" void kernel_launch(void* const* d_in, const int* in_sizes, int n_in,
                              void* d_out, int out_size, void* d_ws, size_t ws_size,
                              hipStream_t stream) {
  const float* x    = (const float*)d_in[0];
  const float* wqkv = (const float*)d_in[1];
  const float* bqkv = (const float*)d_in[2];
  const float* wo   = (const float*)d_in[3];
  const float* bo   = (const float*)d_in[4];

  char* ws = (char*)d_ws;
  const size_t MB = (size_t)1 << 20;
  short* xb          = (short*)(ws + 0);          //  2 MB : x bf16
  short* wqt         = (short*)(ws + 2 * MB);     // .75MB : W_qkv^T bf16
  short* wot         = (short*)(ws + 3 * MB);     // .25MB : W_o^T bf16
  unsigned char* Qf  = (unsigned char*)(ws + 4 * MB);   // 8 MB fp8 [bh][s][c]
  unsigned char* Kf  = (unsigned char*)(ws + 12 * MB);  // 8 MB fp8 [bh][t][c]
  unsigned char* Vt  = (unsigned char*)(ws + 20 * MB);  // 8 MB fp8 [bh][c][t]
  float* Tot8        = (float*)(ws + 28 * MB);          // 16 KB
  short* Part        = (short*)(ws + 29 * MB);          // 32 MB bf16 x2 partials

  hipLaunchKernelGGL(k_cvt_x, dim3(512), dim3(256), 0, stream, x, xb);
  hipLaunchKernelGGL(k_wqkv, dim3(1536), dim3(256), 0, stream, wqkv, wqt);
  hipLaunchKernelGGL(k_wo, dim3(512), dim3(256), 0, stream, wo, wot);
  hipLaunchKernelGGL(k_qkv, dim3(24, 128), dim3(256), 0, stream, xb, wqt, bqkv, Qf, Kf, Vt);
  hipLaunchKernelGGL(k_tot, dim3(1024), dim3(256), 0, stream, Vt, Tot8);
  hipLaunchKernelGGL(k_attn, dim3(256), dim3(512), 0, stream, Qf, Kf, Vt, Part);
  hipLaunchKernelGGL(k_out, dim3(256), dim3(256), 0, stream, Part, Tot8, wot, bo, (float*)d_out);
}